// Round 14
// baseline (110.474 us; speedup 1.0000x reference)
//
#include <hip/hip_runtime.h>
#include <cstdint>
#include <cstddef>

// GraphAttentionLayer fused: B=8, N=2048, D=256
//  k_wh:   Wh = h @ W^T (bf16 MFMA, f32 acc) -> WhT[b][d][n] bf16 + s1,s2 f32
//  k_attn: out[i,:] = (sum_j exp(lrelu(s1_i+s2_j))*mask_ij * Wh[j,:]) / l_i
//    v11: = v10 self-packing fused loop + NON-TEMPORAL adj loads.
//         R13 quantified the wall: 646 MB/block-aggregate reads / 103 us
//         = 6.3 TB/s = saturated L3 fabric, because the adj stream evicts
//         the per-XCD L2-resident WhT panel (1 MB) and pushes all 512 MB of
//         WhT re-reads to L3. `nt` (evict-first) adj loads stop the
//         pollution: WhT -> L2 rate, adj -> streaming, overlapped with MFMA.

#define NB 8
#define NN 2048
#define ND 256
#define ALPHA_F 0.2f
#define JC 64          // j per chunk
#define NCH 16         // chunks per j-group (1024/64)

typedef __attribute__((ext_vector_type(8))) short short8;   // bf16x8 MFMA frag
typedef __attribute__((ext_vector_type(4))) float f32x4;    // MFMA acc frag
typedef __attribute__((ext_vector_type(4))) int   i32x4;

__device__ __forceinline__ unsigned short f2bf(float f) {
  union { float f; unsigned int u; } v; v.f = f;
  unsigned int r = v.u + 0x7FFFu + ((v.u >> 16) & 1u);   // RNE
  return (unsigned short)(r >> 16);
}

__device__ __forceinline__ short8 pack8(const float* v) {
  short8 r;
#pragma unroll
  for (int e = 0; e < 8; ++e) r[e] = (short)f2bf(v[e]);
  return r;
}

__device__ __forceinline__ unsigned int cvtpk(float lo, float hi) {
  unsigned int r;
  asm("v_cvt_pk_bf16_f32 %0, %1, %2" : "=v"(r) : "v"(lo), "v"(hi));
  return r;
}

// ---------------- kernel 1: Wh = h @ W^T, + s1/s2, store WhT bf16 ----------
__global__ __launch_bounds__(256) void k_wh(
    const float* __restrict__ h, const float* __restrict__ W,
    const float* __restrict__ a,
    unsigned short* __restrict__ WhT, float* __restrict__ s1g,
    float* __restrict__ s2g)
{
  __shared__ float sl1[64], sl2[64];
  const int tid  = threadIdx.x;
  const int wid  = tid >> 6;
  const int lane = tid & 63;
  const int l15  = lane & 15;
  const int c    = lane >> 4;
  const int r0   = blockIdx.x * 64;   // flattened (b,n) row base
  const int b    = r0 >> 11;
  const int n0   = r0 & 2047;

  if (tid < 64) { sl1[tid] = 0.f; sl2[tid] = 0.f; }

  f32x4 acc[4][4] = {};

  const float* hb = h + (size_t)r0 * ND;
  const int ocol0 = wid * 64;

  for (int k0 = 0; k0 < ND; k0 += 32) {
    short8 afr[4], bfr[4];
#pragma unroll
    for (int mi = 0; mi < 4; ++mi) {
      const float* p = hb + (size_t)(mi * 16 + l15) * ND + k0 + c * 8;
      float t[8];
      *(f32x4*)t       = *(const f32x4*)p;
      *(f32x4*)(t + 4) = *(const f32x4*)(p + 4);
      afr[mi] = pack8(t);
    }
#pragma unroll
    for (int ni = 0; ni < 4; ++ni) {
      const int o = ocol0 + ni * 16 + l15;
      const float* p = W + (size_t)o * ND + k0 + c * 8;
      float t[8];
      *(f32x4*)t       = *(const f32x4*)p;
      *(f32x4*)(t + 4) = *(const f32x4*)(p + 4);
      bfr[ni] = pack8(t);
    }
#pragma unroll
    for (int mi = 0; mi < 4; ++mi)
#pragma unroll
      for (int ni = 0; ni < 4; ++ni)
        acc[mi][ni] = __builtin_amdgcn_mfma_f32_16x16x32_bf16(
            afr[mi], bfr[ni], acc[mi][ni], 0, 0, 0);
  }

  float a1v[4], a2v[4];
#pragma unroll
  for (int ni = 0; ni < 4; ++ni) {
    const int o = ocol0 + ni * 16 + l15;
    a1v[ni] = a[o];
    a2v[ni] = a[ND + o];
  }
  float p1[4][4] = {}, p2[4][4] = {};
#pragma unroll
  for (int mi = 0; mi < 4; ++mi)
#pragma unroll
    for (int ni = 0; ni < 4; ++ni)
#pragma unroll
      for (int r = 0; r < 4; ++r) {
        p1[mi][r] += acc[mi][ni][r] * a1v[ni];
        p2[mi][r] += acc[mi][ni][r] * a2v[ni];
      }
#pragma unroll
  for (int m = 1; m <= 8; m <<= 1) {
#pragma unroll
    for (int mi = 0; mi < 4; ++mi)
#pragma unroll
      for (int r = 0; r < 4; ++r) {
        p1[mi][r] += __shfl_xor(p1[mi][r], m, 64);
        p2[mi][r] += __shfl_xor(p2[mi][r], m, 64);
      }
  }
  __syncthreads();
  if (l15 == 0) {
#pragma unroll
    for (int mi = 0; mi < 4; ++mi)
#pragma unroll
      for (int r = 0; r < 4; ++r) {
        atomicAdd(&sl1[mi * 16 + c * 4 + r], p1[mi][r]);
        atomicAdd(&sl2[mi * 16 + c * 4 + r], p2[mi][r]);
      }
  }

#pragma unroll
  for (int mi = 0; mi < 4; ++mi)
#pragma unroll
    for (int ni = 0; ni < 4; ++ni) {
      const int o = ocol0 + ni * 16 + l15;
      const int n = n0 + mi * 16 + c * 4;
      unsigned short u4[4];
#pragma unroll
      for (int r = 0; r < 4; ++r) u4[r] = f2bf(acc[mi][ni][r]);
      *(uint2*)(WhT + ((size_t)b * ND + o) * NN + n) = *(uint2*)u4;
    }
  __syncthreads();
  if (tid < 64) { s1g[r0 + tid] = sl1[tid]; s2g[r0 + tid] = sl2[tid]; }
}

// ---------------- kernel 2: self-packing fused attention GEMM (v11) --------
// grid: 512 blocks 1D (b = bid&7 for XCD/L2 locality), 512 thr (8 waves).
// Wave wid: j-group = wid>>2 (half of j-range), col-group = wid&3 (64 cols).
// Build mapping (dense adj): lt=tid&255, row=lt>>3, jseg=lt&7 — one adj
// wave-load covers 8 rows x 256 B contiguous (full lines), loaded with `nt`
// (non-temporal, evict-first) so the 134 MB adj sweep does not evict the
// XCD-L2-resident WhT panel. Per chunk of 64 j: the j-group's 256 threads
// build P[32][64] bf16 in LDS (swizzled) from depth-4 register-prefetched
// adj; 4 waves consume P as MFMA A-frags with bfr (WhT) register-double-
// buffered one chunk ahead. Raw lgkmcnt-only barriers keep all global loads
// in flight across chunks.
__global__ __launch_bounds__(512, 2) void k_attn(
    const int* __restrict__ adj, const unsigned short* __restrict__ WhT,
    const float* __restrict__ s1g, const float* __restrict__ s2g,
    float* __restrict__ out)
{
  __shared__ __align__(16) char smem[32 * 1024 + 128];
  float*          s2s  = (float*)smem;                       // [0, 8K)
  unsigned short* pbuf = (unsigned short*)(smem + 8 * 1024); // [8K,24K): [jg][buf][32][64]
  float*          lsml = (float*)(smem + 32 * 1024);         // [32K, +128)
  float*          comb = (float*)smem;                       // [0,32K) alias after loop

  const int tid  = threadIdx.x;
  const int wid  = tid >> 6;
  const int lane = tid & 63;
  const int l15  = lane & 15;
  const int c    = lane >> 4;
  const int bid  = blockIdx.x;
  const int b    = bid & 7;           // batch -> XCD residue (L2 locality)
  const int i0   = (bid >> 3) * 32;

  // build-phase thread mapping (dense: 8 lanes per row, full-line adj loads)
  const int lt     = tid & 255;
  const int jg     = tid >> 8;        // j-group 0/1 (== wid>>2)
  const int row    = lt >> 3;         // 0..31
  const int jseg   = lt & 7;          // 0..7, 8 j's each
  const int jgbase = jg * (NN / 2);
  const int gsw    = jseg ^ (row & 7);          // swizzled 16B granule
  const int wcol   = wid & 3;

  if (tid < 32) lsml[tid] = 0.f;
  { // stage s2[b][:] into LDS
    const f32x4* src = (const f32x4*)(s2g + (size_t)b * NN);
    f32x4* dst = (f32x4*)s2s;
    for (int t = tid; t < NN / 4; t += 512) dst[t] = src[t];
  }
  const float s1r = s1g[(size_t)b * NN + i0 + row];
  const int* abt = adj + ((size_t)(b * NN + i0 + row)) * NN + jgbase + jseg * 8;

  f32x4 acc[2][4] = {};
  float lacc = 0.f;

  const unsigned short* wb = WhT + ((size_t)b * ND + wcol * 64) * NN;
  unsigned short* pbW[2] = { pbuf + (jg * 2 + 0) * 2048, pbuf + (jg * 2 + 1) * 2048 };

  i32x4 adm[4][2];       // adj prefetch regs, depth 4: [parity][8-int halves]
  short8 bfr[2][2][4];   // [slot][ks][ni] register double-buffer of WhT frags

#define LOADADJ(CH, P)                                                       \
  { const i32x4* ap = (const i32x4*)(abt + (CH) * JC);                       \
    adm[P][0] = __builtin_nontemporal_load(ap);                              \
    adm[P][1] = __builtin_nontemporal_load(ap + 1); }

#define LOADB(CH, SL)                                                        \
  {                                                                          \
    _Pragma("unroll")                                                        \
    for (int ks = 0; ks < 2; ++ks)                                           \
      _Pragma("unroll")                                                      \
      for (int ni = 0; ni < 4; ++ni)                                         \
        bfr[SL][ks][ni] = *(const short8*)(wb + (size_t)(ni * 16 + l15) * NN + \
                                           jgbase + (CH) * JC + ks * 32 + c * 8); \
  }

#define BUILDC(CH, BB, P)                                                    \
  {                                                                          \
    const float* s2p = s2s + jgbase + (CH) * JC + jseg * 8;                  \
    f32x4 sa = *(const f32x4*)s2p;                                           \
    f32x4 sb = *(const f32x4*)(s2p + 4);                                     \
    float pv[8];                                                             \
    _Pragma("unroll")                                                        \
    for (int e = 0; e < 4; ++e) {                                            \
      float ev = s1r + sa[e];                                                \
      ev = fmaxf(ev, ALPHA_F * ev);                                          \
      pv[e] = (adm[P][0][e] > 0) ? __expf(ev) : 0.f;                         \
    }                                                                        \
    _Pragma("unroll")                                                        \
    for (int e = 0; e < 4; ++e) {                                            \
      float ev = s1r + sb[e];                                                \
      ev = fmaxf(ev, ALPHA_F * ev);                                          \
      pv[4 + e] = (adm[P][1][e] > 0) ? __expf(ev) : 0.f;                     \
    }                                                                        \
    lacc += ((pv[0] + pv[1]) + (pv[2] + pv[3])) +                            \
            ((pv[4] + pv[5]) + (pv[6] + pv[7]));                             \
    i32x4 pk;                                                                \
    pk[0] = (int)cvtpk(pv[0], pv[1]);                                        \
    pk[1] = (int)cvtpk(pv[2], pv[3]);                                        \
    pk[2] = (int)cvtpk(pv[4], pv[5]);                                        \
    pk[3] = (int)cvtpk(pv[6], pv[7]);                                        \
    *(i32x4*)(pbW[BB] + row * 64 + gsw * 8) = pk;                            \
  }

  // raw barrier: drain LDS ops only; global loads stay counted (T4)
#define CHUNK_BARRIER()                                                      \
  { asm volatile("s_waitcnt lgkmcnt(0)" ::: "memory");                       \
    __builtin_amdgcn_s_barrier(); }

  // prologue: adj chunks 0..3 in flight, then one full drain (also covers s2s)
  LOADADJ(0, 0)
  LOADADJ(1, 1)
  LOADADJ(2, 2)
  LOADADJ(3, 3)
  __syncthreads();   // s2s + lsml ready (one-time full drain is fine)

  BUILDC(0, 0, 0)
  LOADADJ(4, 0)      // refill parity 0 (consume-then-refill)
  LOADB(0, 0)        // chunk 0's bfr: issued before barrier, used after
  CHUNK_BARRIER()

#pragma unroll
  for (int ch = 0; ch < NCH; ++ch) {
    const int bb = ch & 1;
    const unsigned short* pbR = pbW[bb];
    // issue next chunk's bfr first (oldest in queue -> its wait never drains
    // the younger deep adj prefetch)
    if (ch + 1 < NCH) LOADB(ch + 1, (ch + 1) & 1)
    if (ch + 1 < NCH) {
      // consume adm[(ch+1)&3] (loaded 4 chunks ago) THEN refill same parity
      BUILDC(ch + 1, (ch + 1) & 1, (ch + 1) & 3)
      if (ch + 5 < NCH) LOADADJ(ch + 5, (ch + 5) & 3)
    }
    // consume current bfr (in flight since previous iteration)
#pragma unroll
    for (int ks = 0; ks < 2; ++ks) {
      short8 a0 = *(const short8*)(pbR + (0 * 16 + l15) * 64 +
                                   (((ks * 4 + c) ^ (l15 & 7)) * 8));
      short8 a1 = *(const short8*)(pbR + (1 * 16 + l15) * 64 +
                                   (((ks * 4 + c) ^ (l15 & 7)) * 8));
#pragma unroll
      for (int ni = 0; ni < 4; ++ni) {
        acc[0][ni] = __builtin_amdgcn_mfma_f32_16x16x32_bf16(
            a0, bfr[bb][ks][ni], acc[0][ni], 0, 0, 0);
        acc[1][ni] = __builtin_amdgcn_mfma_f32_16x16x32_bf16(
            a1, bfr[bb][ks][ni], acc[1][ni], 0, 0, 0);
      }
    }
    CHUNK_BARRIER()
  }

  // lsum: per-thread partial -> per-row total (8 threads/row/jg, plain atomic)
  atomicAdd(&lsml[row], lacc);
  __syncthreads();

  // combine j-group partial accumulators via LDS
  if (jg == 1) {
#pragma unroll
    for (int mi = 0; mi < 2; ++mi)
#pragma unroll
      for (int r = 0; r < 4; ++r) {
        const int rr = mi * 16 + c * 4 + r;
#pragma unroll
        for (int ni = 0; ni < 4; ++ni)
          comb[rr * ND + wcol * 64 + ni * 16 + l15] = acc[mi][ni][r];
      }
  }
  __syncthreads();
  if (jg == 0) {
    float* ob = out + ((size_t)b * NN + i0) * ND + wcol * 64;
#pragma unroll
    for (int mi = 0; mi < 2; ++mi)
#pragma unroll
      for (int r = 0; r < 4; ++r) {
        const int rr = mi * 16 + c * 4 + r;
        const float linv = 1.0f / lsml[rr];
#pragma unroll
        for (int ni = 0; ni < 4; ++ni) {
          const float v = acc[mi][ni][r] + comb[rr * ND + wcol * 64 + ni * 16 + l15];
          ob[(size_t)rr * ND + ni * 16 + l15] = v * linv;
        }
      }
  }
#undef BUILDC
#undef LOADB
#undef LOADADJ
#undef CHUNK_BARRIER
}

extern "C" void kernel_launch(void* const* d_in, const int* in_sizes, int n_in,
                              void* d_out, int out_size, void* d_ws, size_t ws_size,
                              hipStream_t stream) {
  const float* h   = (const float*)d_in[0];
  const int*   adj = (const int*)d_in[1];
  const float* W   = (const float*)d_in[2];
  const float* a   = (const float*)d_in[3];
  float* out = (float*)d_out;

  unsigned short* WhT = (unsigned short*)d_ws;                       // 8 MB bf16
  float* s1g = (float*)((char*)d_ws + (size_t)NB * ND * NN * 2);     // 64 KB
  float* s2g = s1g + (size_t)NB * NN;                                // 64 KB

  k_wh<<<dim3(NB * NN / 64), dim3(256), 0, stream>>>(h, W, a, WhT, s1g, s2g);
  k_attn<<<dim3(NB * NN / 32), dim3(512), 0, stream>>>(adj, WhT, s1g, s2g, out);
}

// Round 15
// 65.579 us; speedup vs baseline: 1.6846x; 1.6846x over previous
//
#include <hip/hip_runtime.h>
#include <cstdint>
#include <cstddef>

// GraphAttentionLayer fused: B=8, N=2048, D=256
//  k_wh:   Wh = h @ W^T (bf16 MFMA, f32 acc) -> WhT[b][d][n] bf16 + s1,s2 f32
//  k_attn: out[i,:] = (sum_j exp(lrelu(s1_i+s2_j))*mask_ij * Wh[j,:]) / l_i
//    v12: 64 i-rows/block (256 blocks): halves the dominant WhT panel
//         re-read traffic (512->256 MB) at the measured ~7 TB/s L3-fabric
//         roofline. No jg split: all 8 waves share the full j-range, wave w
//         owns a 32-col output slice -> no comb epilogue, smaller acc.
//         nt loads REVERTED (R14: profiled -14 us but timed +12 us — nt
//         kills the inter-replay L3 residency of adj).

#define NB 8
#define NN 2048
#define ND 256
#define ALPHA_F 0.2f
#define JC 64           // j per chunk
#define NCH2 32         // chunks (2048/64)
#define IR 64           // i-rows per block

typedef __attribute__((ext_vector_type(8))) short short8;   // bf16x8 MFMA frag
typedef __attribute__((ext_vector_type(4))) float f32x4;    // MFMA acc frag
typedef __attribute__((ext_vector_type(4))) int   i32x4;

__device__ __forceinline__ unsigned short f2bf(float f) {
  union { float f; unsigned int u; } v; v.f = f;
  unsigned int r = v.u + 0x7FFFu + ((v.u >> 16) & 1u);   // RNE
  return (unsigned short)(r >> 16);
}

__device__ __forceinline__ short8 pack8(const float* v) {
  short8 r;
#pragma unroll
  for (int e = 0; e < 8; ++e) r[e] = (short)f2bf(v[e]);
  return r;
}

__device__ __forceinline__ unsigned int cvtpk(float lo, float hi) {
  unsigned int r;
  asm("v_cvt_pk_bf16_f32 %0, %1, %2" : "=v"(r) : "v"(lo), "v"(hi));
  return r;
}

// ---------------- kernel 1: Wh = h @ W^T, + s1/s2, store WhT bf16 ----------
__global__ __launch_bounds__(256) void k_wh(
    const float* __restrict__ h, const float* __restrict__ W,
    const float* __restrict__ a,
    unsigned short* __restrict__ WhT, float* __restrict__ s1g,
    float* __restrict__ s2g)
{
  __shared__ float sl1[64], sl2[64];
  const int tid  = threadIdx.x;
  const int wid  = tid >> 6;
  const int lane = tid & 63;
  const int l15  = lane & 15;
  const int c    = lane >> 4;
  const int r0   = blockIdx.x * 64;   // flattened (b,n) row base
  const int b    = r0 >> 11;
  const int n0   = r0 & 2047;

  if (tid < 64) { sl1[tid] = 0.f; sl2[tid] = 0.f; }

  f32x4 acc[4][4] = {};

  const float* hb = h + (size_t)r0 * ND;
  const int ocol0 = wid * 64;

  for (int k0 = 0; k0 < ND; k0 += 32) {
    short8 afr[4], bfr[4];
#pragma unroll
    for (int mi = 0; mi < 4; ++mi) {
      const float* p = hb + (size_t)(mi * 16 + l15) * ND + k0 + c * 8;
      float t[8];
      *(f32x4*)t       = *(const f32x4*)p;
      *(f32x4*)(t + 4) = *(const f32x4*)(p + 4);
      afr[mi] = pack8(t);
    }
#pragma unroll
    for (int ni = 0; ni < 4; ++ni) {
      const int o = ocol0 + ni * 16 + l15;
      const float* p = W + (size_t)o * ND + k0 + c * 8;
      float t[8];
      *(f32x4*)t       = *(const f32x4*)p;
      *(f32x4*)(t + 4) = *(const f32x4*)(p + 4);
      bfr[ni] = pack8(t);
    }
#pragma unroll
    for (int mi = 0; mi < 4; ++mi)
#pragma unroll
      for (int ni = 0; ni < 4; ++ni)
        acc[mi][ni] = __builtin_amdgcn_mfma_f32_16x16x32_bf16(
            afr[mi], bfr[ni], acc[mi][ni], 0, 0, 0);
  }

  float a1v[4], a2v[4];
#pragma unroll
  for (int ni = 0; ni < 4; ++ni) {
    const int o = ocol0 + ni * 16 + l15;
    a1v[ni] = a[o];
    a2v[ni] = a[ND + o];
  }
  float p1[4][4] = {}, p2[4][4] = {};
#pragma unroll
  for (int mi = 0; mi < 4; ++mi)
#pragma unroll
    for (int ni = 0; ni < 4; ++ni)
#pragma unroll
      for (int r = 0; r < 4; ++r) {
        p1[mi][r] += acc[mi][ni][r] * a1v[ni];
        p2[mi][r] += acc[mi][ni][r] * a2v[ni];
      }
#pragma unroll
  for (int m = 1; m <= 8; m <<= 1) {
#pragma unroll
    for (int mi = 0; mi < 4; ++mi)
#pragma unroll
      for (int r = 0; r < 4; ++r) {
        p1[mi][r] += __shfl_xor(p1[mi][r], m, 64);
        p2[mi][r] += __shfl_xor(p2[mi][r], m, 64);
      }
  }
  __syncthreads();
  if (l15 == 0) {
#pragma unroll
    for (int mi = 0; mi < 4; ++mi)
#pragma unroll
      for (int r = 0; r < 4; ++r) {
        atomicAdd(&sl1[mi * 16 + c * 4 + r], p1[mi][r]);
        atomicAdd(&sl2[mi * 16 + c * 4 + r], p2[mi][r]);
      }
  }

#pragma unroll
  for (int mi = 0; mi < 4; ++mi)
#pragma unroll
    for (int ni = 0; ni < 4; ++ni) {
      const int o = ocol0 + ni * 16 + l15;
      const int n = n0 + mi * 16 + c * 4;
      unsigned short u4[4];
#pragma unroll
      for (int r = 0; r < 4; ++r) u4[r] = f2bf(acc[mi][ni][r]);
      *(uint2*)(WhT + ((size_t)b * ND + o) * NN + n) = *(uint2*)u4;
    }
  __syncthreads();
  if (tid < 64) { s1g[r0 + tid] = sl1[tid]; s2g[r0 + tid] = sl2[tid]; }
}

// ---------------- kernel 2: self-packing fused attention GEMM (v12) --------
// grid: 256 blocks 1D (b = bid&7 for XCD/L2 locality), 512 thr (8 waves).
// Block = 64 i-rows x full j-range. Wave w owns output cols [w*32, w*32+32).
// Build mapping: row = tid>>3 (0..63), jseg = tid&7 — one adj wave-load
// covers 8 rows x 256 B contiguous (full lines). Per chunk of 64 j: all 512
// threads build P[64][64] bf16 in LDS (swizzled) from depth-4 register-
// prefetched adj; each wave consumes P as MFMA A-frags (4 row-frags x its
// 2 col-frags) with bfr (WhT) register-double-buffered one chunk ahead.
// Raw lgkmcnt-only barriers keep global loads in flight across chunks.
// No jg combine: each wave owns its cols over the FULL j-range.
__global__ __launch_bounds__(512, 2) void k_attn(
    const int* __restrict__ adj, const unsigned short* __restrict__ WhT,
    const float* __restrict__ s1g, const float* __restrict__ s2g,
    float* __restrict__ out)
{
  __shared__ __align__(16) float s2s[NN];                    // 8 KB
  __shared__ __align__(16) unsigned short pbuf[2][IR * JC];  // 16 KB
  __shared__ float lsml[IR];

  const int tid  = threadIdx.x;
  const int wid  = tid >> 6;          // wave = col-group (32 cols)
  const int lane = tid & 63;
  const int l15  = lane & 15;
  const int c    = lane >> 4;
  const int bid  = blockIdx.x;
  const int b    = bid & 7;           // batch -> XCD residue (L2 locality)
  const int i0   = (bid >> 3) * IR;

  // build-phase thread mapping (dense: 8 lanes per row, full-line adj loads)
  const int row  = tid >> 3;          // 0..63
  const int jseg = tid & 7;           // 0..7, 8 j's each
  const int gsw  = jseg ^ (row & 7);  // swizzled 16B granule

  if (tid < IR) lsml[tid] = 0.f;
  { // stage s2[b][:] into LDS
    const f32x4* src = (const f32x4*)(s2g + (size_t)b * NN);
    f32x4* dst = (f32x4*)s2s;
    for (int t = tid; t < NN / 4; t += 512) dst[t] = src[t];
  }
  const float s1r = s1g[(size_t)b * NN + i0 + row];
  const int* abt = adj + ((size_t)(b * NN + i0 + row)) * NN + jseg * 8;

  f32x4 acc[4][2] = {};
  float lacc = 0.f;

  const unsigned short* wb = WhT + ((size_t)b * ND + wid * 32) * NN;

  i32x4 adm[4][2];       // adj prefetch regs, depth 4: [parity][8-int halves]
  short8 bfr[2][2][2];   // [slot][ks][ni] register double-buffer of WhT frags

#define LOADADJ(CH, P)                                                       \
  { const int* ap = abt + (CH) * JC;                                         \
    adm[P][0] = *(const i32x4*)ap;                                           \
    adm[P][1] = *(const i32x4*)(ap + 4); }

#define LOADB(CH, SL)                                                        \
  {                                                                          \
    _Pragma("unroll")                                                        \
    for (int ks = 0; ks < 2; ++ks)                                           \
      _Pragma("unroll")                                                      \
      for (int ni = 0; ni < 2; ++ni)                                         \
        bfr[SL][ks][ni] = *(const short8*)(wb + (size_t)(ni * 16 + l15) * NN + \
                                           (CH) * JC + ks * 32 + c * 8);     \
  }

#define BUILDC(CH, BB, P)                                                    \
  {                                                                          \
    const float* s2p = s2s + (CH) * JC + jseg * 8;                           \
    f32x4 sa = *(const f32x4*)s2p;                                           \
    f32x4 sb = *(const f32x4*)(s2p + 4);                                     \
    float pv[8];                                                             \
    _Pragma("unroll")                                                        \
    for (int e = 0; e < 4; ++e) {                                            \
      float ev = s1r + sa[e];                                                \
      ev = fmaxf(ev, ALPHA_F * ev);                                          \
      pv[e] = (adm[P][0][e] > 0) ? __expf(ev) : 0.f;                         \
    }                                                                        \
    _Pragma("unroll")                                                        \
    for (int e = 0; e < 4; ++e) {                                            \
      float ev = s1r + sb[e];                                                \
      ev = fmaxf(ev, ALPHA_F * ev);                                          \
      pv[4 + e] = (adm[P][1][e] > 0) ? __expf(ev) : 0.f;                     \
    }                                                                        \
    lacc += ((pv[0] + pv[1]) + (pv[2] + pv[3])) +                            \
            ((pv[4] + pv[5]) + (pv[6] + pv[7]));                             \
    i32x4 pk;                                                                \
    pk[0] = (int)cvtpk(pv[0], pv[1]);                                        \
    pk[1] = (int)cvtpk(pv[2], pv[3]);                                        \
    pk[2] = (int)cvtpk(pv[4], pv[5]);                                        \
    pk[3] = (int)cvtpk(pv[6], pv[7]);                                        \
    *(i32x4*)(&pbuf[BB][0] + row * JC + gsw * 8) = pk;                       \
  }

  // raw barrier: drain LDS ops only; global loads stay counted (T4)
#define CHUNK_BARRIER()                                                      \
  { asm volatile("s_waitcnt lgkmcnt(0)" ::: "memory");                       \
    __builtin_amdgcn_s_barrier(); }

  // prologue: adj chunks 0..3 in flight, then one full drain (covers s2s too)
  LOADADJ(0, 0)
  LOADADJ(1, 1)
  LOADADJ(2, 2)
  LOADADJ(3, 3)
  __syncthreads();   // s2s + lsml ready (one-time full drain is fine)

  BUILDC(0, 0, 0)
  LOADADJ(4, 0)      // refill parity 0 (consume-then-refill)
  LOADB(0, 0)        // chunk 0's bfr: issued before barrier, used after
  CHUNK_BARRIER()

#pragma unroll
  for (int ch = 0; ch < NCH2; ++ch) {
    const int bb = ch & 1;
    const unsigned short* pbR = &pbuf[bb][0];
    // issue next chunk's bfr first (oldest in queue -> its wait never drains
    // the younger deep adj prefetch)
    if (ch + 1 < NCH2) LOADB(ch + 1, (ch + 1) & 1)
    if (ch + 1 < NCH2) {
      // consume adm[(ch+1)&3] (loaded 4 chunks ago) THEN refill same parity
      BUILDC(ch + 1, (ch + 1) & 1, (ch + 1) & 3)
      if (ch + 5 < NCH2) LOADADJ(ch + 5, (ch + 5) & 3)
    }
    // consume current bfr (in flight since previous iteration)
#pragma unroll
    for (int ks = 0; ks < 2; ++ks) {
#pragma unroll
      for (int mi = 0; mi < 4; ++mi) {
        short8 am = *(const short8*)(pbR + (mi * 16 + l15) * JC +
                                     (((ks * 4 + c) ^ (l15 & 7)) * 8));
#pragma unroll
        for (int ni = 0; ni < 2; ++ni)
          acc[mi][ni] = __builtin_amdgcn_mfma_f32_16x16x32_bf16(
              am, bfr[bb][ks][ni], acc[mi][ni], 0, 0, 0);
      }
    }
    CHUNK_BARRIER()
  }

  // lsum: reduce the 8 jseg-lanes of each row (adjacent lanes), one atomic
  lacc += __shfl_xor(lacc, 1, 64);
  lacc += __shfl_xor(lacc, 2, 64);
  lacc += __shfl_xor(lacc, 4, 64);
  if ((lane & 7) == 0) atomicAdd(&lsml[row], lacc);
  __syncthreads();

  // epilogue: direct write (each wave owns its 32 cols over the full j-range)
  float* ob = out + ((size_t)b * NN + i0) * ND + wid * 32;
#pragma unroll
  for (int mi = 0; mi < 4; ++mi)
#pragma unroll
    for (int r = 0; r < 4; ++r) {
      const int rr = mi * 16 + c * 4 + r;
      const float linv = 1.0f / lsml[rr];
#pragma unroll
      for (int ni = 0; ni < 2; ++ni)
        ob[(size_t)rr * ND + ni * 16 + l15] = acc[mi][ni][r] * linv;
    }
#undef BUILDC
#undef LOADB
#undef LOADADJ
#undef CHUNK_BARRIER
}

extern "C" void kernel_launch(void* const* d_in, const int* in_sizes, int n_in,
                              void* d_out, int out_size, void* d_ws, size_t ws_size,
                              hipStream_t stream) {
  const float* h   = (const float*)d_in[0];
  const int*   adj = (const int*)d_in[1];
  const float* W   = (const float*)d_in[2];
  const float* a   = (const float*)d_in[3];
  float* out = (float*)d_out;

  unsigned short* WhT = (unsigned short*)d_ws;                       // 8 MB bf16
  float* s1g = (float*)((char*)d_ws + (size_t)NB * ND * NN * 2);     // 64 KB
  float* s2g = s1g + (size_t)NB * NN;                                // 64 KB

  k_wh<<<dim3(NB * NN / 64), dim3(256), 0, stream>>>(h, W, a, WhT, s1g, s2g);
  k_attn<<<dim3(NB * NN / IR), dim3(512), 0, stream>>>(adj, WhT, s1g, s2g, out);
}